// Round 6
// baseline (45.508 us; speedup 1.0000x reference)
//
#include <hip/hip_runtime.h>

#define IN_DIM   256
#define OUT_DIM  128
#define IN_SEQ   512
#define OUT_SEQ  512
#define NUM_BASIS 16
#define LN_EPS   1e-5f

typedef float f16v __attribute__((ext_vector_type(16)));

__device__ __forceinline__ float cosrev(float x) {
  // cos(2*pi*x): v_fract then v_cos (revolutions semantics)
  return __builtin_amdgcn_cosf(__builtin_amdgcn_fractf(x));
}

// ---------------------------------------------------------------------------
// Kernel 1: Z = x @ M.T (one block per k), LayerNorm -> Zn, ZT.
// Also zero-initializes out for kernel 2's atomic accumulation.
// ---------------------------------------------------------------------------
__global__ __launch_bounds__(256) void k_prep(const float* __restrict__ x,
                                              const float* __restrict__ M,
                                              const float* __restrict__ gamma,
                                              const float* __restrict__ beta,
                                              float* __restrict__ Zn,
                                              float* __restrict__ ZT,
                                              float* __restrict__ out) {
  const int k = blockIdx.x;
  const int t = threadIdx.x;
  __shared__ __align__(16) float xk[IN_DIM];
  __shared__ float red[256];
  __shared__ float stats[8];

  xk[t] = x[k * IN_DIM + t];
  if (t < 128) out[k * OUT_DIM + t] = 0.f;   // zero-init for K2's atomics
  __syncthreads();

  const int j = t & 127;
  const int h = t >> 7;  // which half of the 256-dim input
  const float4* __restrict__ M4 =
      reinterpret_cast<const float4*>(M + j * IN_DIM + h * 128);
  const float4* __restrict__ x4 = reinterpret_cast<const float4*>(xk + h * 128);
  float acc = 0.f;
#pragma unroll 8
  for (int c = 0; c < 32; ++c) {
    float4 m = M4[c];
    float4 xv = x4[c];
    acc = fmaf(m.x, xv.x, acc);
    acc = fmaf(m.y, xv.y, acc);
    acc = fmaf(m.z, xv.z, acc);
    acc = fmaf(m.w, xv.w, acc);
  }
  red[t] = acc;
  __syncthreads();

  float z = 0.f;
  if (t < 128) z = red[t] + red[t + 128];

  float s1 = (t < 128) ? z : 0.f;
  float s2 = (t < 128) ? z * z : 0.f;
#pragma unroll
  for (int m = 1; m < 64; m <<= 1) {
    s1 += __shfl_xor(s1, m);
    s2 += __shfl_xor(s2, m);
  }
  const int w = t >> 6;
  if ((t & 63) == 0) {
    stats[w] = s1;
    stats[4 + w] = s2;
  }
  __syncthreads();
  const float mu  = (stats[0] + stats[1] + stats[2] + stats[3]) * (1.f / 128.f);
  const float msq = (stats[4] + stats[5] + stats[6] + stats[7]) * (1.f / 128.f);
  const float rs  = rsqrtf(msq - mu * mu + LN_EPS);

  if (t < 128) {
    float zn = (z - mu) * rs * gamma[t] + beta[t];
    Zn[k * OUT_DIM + t] = zn;     // coalesced
    ZT[t * IN_SEQ + k] = z;       // scattered 4B, tiny total
  }
}

// ---------------------------------------------------------------------------
// Kernel 2: fused position transform + sequence transform.
// Block = (chunk 0..3 of 128 k, output channel i). 256 threads = (j, k-half).
// Phase B: Chebyshev recurrence c(k+1)=2cos(2pi/p)c(k)-c(k-1) per (j,g).
//   State held as ext_vector_type(16) SSA values (Pv,tc,c0,c1) — pure vector
//   ops in the recurrence, constant-index extracts in the dot — so the
//   compiler CANNOT demote them to scratch (round-5: float[16] arrays gave
//   VGPR_Count=52 -> spilled -> 40us latency-bound at 20% VALUBusy).
// Phase C: out[s,i] += sum_{k in chunk} L[k,s] * vcol[k] via one atomicAdd
//   per (s,i,chunk); 4 contenders per address.
// ---------------------------------------------------------------------------
__global__ __launch_bounds__(256) void k_bc(const float* __restrict__ P,
                                            const float* __restrict__ L,
                                            const float* __restrict__ Zn,
                                            const float* __restrict__ ZT,
                                            float* __restrict__ out) {
  const int chunk = blockIdx.x;     // 0..3, 128 k each
  const int i     = blockIdx.y;     // 0..127
  const int t     = threadIdx.x;
  const int j     = t & 127;
  const int kh    = t >> 7;         // k-half within chunk
  const int w01   = (t >> 6) & 1;   // j-half parity (wave within the k-half)
  const int ks0   = chunk * 128 + kh * 64;

  __shared__ float redB[128 * 2];
  __shared__ float vcol[128];

  // --- per-(i,j,g) state in ext-vector registers ---
  f16v Pv, tc, c0, c1;
  {
    const float4* __restrict__ P4 =
        reinterpret_cast<const float4*>(P + (size_t)(i * OUT_DIM + j) * NUM_BASIS);
    float4 a = P4[0], b = P4[1], c = P4[2], d = P4[3];
    Pv = (f16v){a.x, a.y, a.z, a.w, b.x, b.y, b.z, b.w,
                c.x, c.y, c.z, c.w, d.x, d.y, d.z, d.w};
  }
  const int pb = i * (OUT_DIM * NUM_BASIS) + j * NUM_BASIS + 2;
  const float km1 = (float)(ks0 - 1);   // k=-1 ok: cos is even
  const float kcu = (float)ks0;
#pragma unroll
  for (int g = 0; g < NUM_BASIS; ++g) {
    float pinv = 1.0f / (float)(pb + g);          // p >= 2 -> pinv <= 0.5
    tc[g] = 2.0f * __builtin_amdgcn_cosf(pinv);   // 2*cos(2*pi/p)
    c0[g] = cosrev(km1 * pinv);
    c1[g] = cosrev(kcu * pinv);
  }

  // --- Phase B: 64 serial k-steps (8 groups of 8) ---
  const float* __restrict__ znj = Zn + j;
  float buf[8];
#pragma unroll
  for (int r = 0; r < 8; ++r) buf[r] = znj[(ks0 + r) * OUT_DIM];

  for (int kg = 0; kg < 8; ++kg) {
    float nbuf[8];
#pragma unroll
    for (int r = 0; r < 8; ++r) {
      // final group's prefetch reads past Zn into the adjacent ZT workspace
      // region (allocated; values unused).
      nbuf[r] = znj[(ks0 + (kg + 1) * 8 + r) * OUT_DIM];
    }
    float v[8];
#pragma unroll
    for (int r = 0; r < 8; ++r) {
      f16v prod = Pv * c1;
      float s = ((((prod[0] + prod[1]) + (prod[2] + prod[3])) +
                  ((prod[4] + prod[5]) + (prod[6] + prod[7]))) +
                 (((prod[8] + prod[9]) + (prod[10] + prod[11])) +
                  ((prod[12] + prod[13]) + (prod[14] + prod[15]))));
      v[r] = buf[r] * s;
      f16v cn = tc * c1 - c0;   // 16 vector FMAs, no indexing
      c0 = c1;
      c1 = cn;
    }
#pragma unroll
    for (int m = 1; m < 64; m <<= 1) {
#pragma unroll
      for (int r = 0; r < 8; ++r) v[r] += __shfl_xor(v[r], m);
    }
    if ((t & 63) == 0) {
#pragma unroll
      for (int r = 0; r < 8; ++r) redB[(kh * 64 + kg * 8 + r) * 2 + w01] = v[r];
    }
#pragma unroll
    for (int r = 0; r < 8; ++r) buf[r] = nbuf[r];
  }

  __syncthreads();
  if (t < 128) {
    const int k = chunk * 128 + t;
    vcol[t] = redB[t * 2] + redB[t * 2 + 1] + ZT[i * IN_SEQ + k];
  }
  __syncthreads();

  // --- Phase C: rank-128 update of out column i ---
  const float* __restrict__ Lb = L + (size_t)chunk * 128 * OUT_SEQ;
  float acc0 = 0.f, acc1 = 0.f;
#pragma unroll 4
  for (int kk = 0; kk < 128; ++kk) {
    const float v = vcol[kk];                 // LDS broadcast
    acc0 = fmaf(Lb[kk * OUT_SEQ + t], v, acc0);        // s = t
    acc1 = fmaf(Lb[kk * OUT_SEQ + t + 256], v, acc1);  // s = t + 256
  }
  atomicAdd(&out[t * OUT_DIM + i], acc0);
  atomicAdd(&out[(t + 256) * OUT_DIM + i], acc1);
}

extern "C" void kernel_launch(void* const* d_in, const int* in_sizes, int n_in,
                              void* d_out, int out_size, void* d_ws, size_t ws_size,
                              hipStream_t stream) {
  const float* x      = (const float*)d_in[0];
  const float* M      = (const float*)d_in[1];
  const float* P      = (const float*)d_in[2];
  const float* Linker = (const float*)d_in[3];
  const float* gamma  = (const float*)d_in[4];
  const float* beta   = (const float*)d_in[5];
  // d_in[6] = periods (recomputed inline: p = i*2048 + j*16 + g + 2, exact in f32)
  float* out = (float*)d_out;

  float* ws = (float*)d_ws;
  float* Zn = ws;                        // 512*128
  float* ZT = ws + IN_SEQ * OUT_DIM;     // 128*512 (pre-LN Z, transposed)

  k_prep<<<dim3(IN_SEQ), dim3(256), 0, stream>>>(x, M, gamma, beta, Zn, ZT, out);
  k_bc<<<dim3(4, OUT_DIM), dim3(256), 0, stream>>>(P, Linker, Zn, ZT, out);
}